// Round 22
// baseline (204.575 us; speedup 1.0000x reference)
//
#include <hip/hip_runtime.h>
#include <hip/hip_bf16.h>
#include <math.h>

#define D      256
#define N2     8192
#define NHALF  4096
#define TILE   128
#define BK     64
#define NCH    4       // 256 / BK
#define LDW    68      // 136B row stride: r5/r13/r14-verified 0-conflict maps
#define NTRI   2080    // 64*65/2 triangular tiles (bi <= bj)
#define TPB    512     // 8 waves/block, 2 blocks/CU -> 4 waves/SIMD (r16-verified)

typedef __bf16 bf16x8_t __attribute__((ext_vector_type(8)));
typedef float  f32x4_t  __attribute__((ext_vector_type(4)));

// ---------------- single fused kernel: claim-based prep + r16 sim + ticket fin -----
// r21 post-mortem: hang was a barrier-divergence race -- claim()'s st==2 path had no
// trailing __syncthreads, so claim(bj) could overwrite shared `clm` while siblings
// still read it for claim(bi); a stale-read of 1 entered the spin path's extra
// barrier that tid0 never took -> intra-block barrier mismatch -> deadlock.
// Fixes: (1) unconditional trailing __syncthreads in claim() (clm never reused while
// live; branch uniform per block); (2) BOUNDED spin with idempotent fallback -- on
// timeout the block preps the panel itself (same input -> same output bytes, safe
// to duplicate) -> kernel terminates unconditionally. All atomics relaxed/agent
// (no L2-invalidating fences, r10 lesson). Sim body byte-identical to r16 (47.2us);
// positives via r13-verified sub-diagonal path; two-level fenceless tickets (r16).
__global__ __launch_bounds__(TPB, 4) void sim_kernel(const float* __restrict__ a,
                                                     const float* __restrict__ b,
                                                     __bf16* __restrict__ zb,
                                                     float* __restrict__ g_denom,
                                                     float* __restrict__ g_pos,
                                                     unsigned* __restrict__ g_t1,
                                                     unsigned* __restrict__ g_flag,
                                                     float* __restrict__ out) {
    __shared__ __bf16 ldsA[2][TILE * LDW];
    __shared__ __bf16 ldsB[2][TILE * LDW];
    __shared__ float  sw[8];
    __shared__ int    clm;
    __shared__ bool   amLast;

    const int tid    = threadIdx.x;
    const int l      = tid & 63;
    const int lane15 = l & 15;
    const int quad   = l >> 4;
    const int w      = tid >> 6;               // wave 0..7
    const int wr     = (w & 3) * 32;           // wave rows: 32
    const int wc     = (w >> 2) * 64;          // wave cols: 64

    // triangular decode: k -> (bi, bj), bi <= bj
    const int bx = blockIdx.x;
    const int k  = bx;
    int bi = (int)(64.5f - sqrtf(64.5f * 64.5f - 2.0f * (float)k));
    while ((bi * (129 - bi)) / 2 > k) --bi;
    while (((bi + 1) * (128 - bi)) / 2 <= k) ++bi;
    const int bj   = bi + (k - (bi * (129 - bi)) / 2);
    const bool diag = (bi == bj);

    // ---------------- claim-based prep (idempotent; hang-proof) ----------------
    auto prep_panel = [&](int panel) {
        const int pr = tid >> 2;               // 0..127 row in panel
        const int pq = tid & 3;                // quarter (64 f32)
        const int g  = panel * TILE + pr;      // global z-row
        const float* src = (g < NHALF) ? (a + (size_t)g * D + pq * 64)
                                       : (b + (size_t)(g - NHALF) * D + pq * 64);
        float ss = 0.f;
        #pragma unroll
        for (int i = 0; i < 16; ++i) {
            f32x4_t v = *(const f32x4_t*)(src + i * 4);
            ss += v[0]*v[0] + v[1]*v[1] + v[2]*v[2] + v[3]*v[3];
        }
        ss += __shfl_xor(ss, 1, 64);
        ss += __shfl_xor(ss, 2, 64);
        const float rn = 1.0f / fmaxf(sqrtf(ss), 1e-8f);
        unsigned* dst = (unsigned*)(zb + (size_t)g * D) + pq * 32;
        #pragma unroll
        for (int i = 0; i < 16; ++i) {        // reload (L1-hot), convert, atomic store
            f32x4_t v = *(const f32x4_t*)(src + i * 4);
            #pragma unroll
            for (int e = 0; e < 2; ++e) {
                __bf16 lo = (__bf16)(v[2*e]     * rn);
                __bf16 hi = (__bf16)(v[2*e + 1] * rn);
                unsigned u = ((unsigned)(*(unsigned short*)&hi) << 16)
                           | (unsigned)(*(unsigned short*)&lo);
                __hip_atomic_store(dst + i * 2 + e, u, __ATOMIC_RELAXED,
                                   __HIP_MEMORY_SCOPE_AGENT);
            }
        }
    };
    auto claim = [&](int panel) {
        if (tid == 0) {
            unsigned exp0 = 0u;
            bool won = __hip_atomic_compare_exchange_strong(
                &g_flag[panel], &exp0, 1u, __ATOMIC_RELAXED, __ATOMIC_RELAXED,
                __HIP_MEMORY_SCOPE_AGENT);
            clm = won ? 0 : (int)exp0;         // 0=claimed, 1=in progress, 2=done
        }
        __syncthreads();
        const int st = clm;
        if (st == 0) {
            prep_panel(panel);
            __syncthreads();                   // all waves' stores drained (vmcnt0)
            if (tid == 0)
                __hip_atomic_store(&g_flag[panel], 2u, __ATOMIC_RELAXED,
                                   __HIP_MEMORY_SCOPE_AGENT);
        } else if (st == 1) {
            if (tid == 0) {
                int it = 0;
                while (__hip_atomic_load(&g_flag[panel], __ATOMIC_RELAXED,
                                         __HIP_MEMORY_SCOPE_AGENT) != 2u
                       && it < 300000) {
                    __builtin_amdgcn_s_sleep(4);
                    ++it;
                }
                clm = (__hip_atomic_load(&g_flag[panel], __ATOMIC_RELAXED,
                                         __HIP_MEMORY_SCOPE_AGENT) == 2u) ? 2 : 3;
            }
            __syncthreads();
            if (clm == 3) {                    // timeout fallback: idempotent re-prep
                prep_panel(panel);
                __syncthreads();
            }
        }
        __syncthreads();                       // protect clm reuse; all see prep done
    };
    claim(bi);
    if (!diag) claim(bj);

    // ---------------- r16 sim body (byte-identical) ----------------
    const int r = tid >> 2;
    const int q = tid & 3;
    const __bf16* ga = zb + (size_t)(bi * TILE + r) * D + q * 16;
    const __bf16* gb = zb + (size_t)(bj * TILE + r) * D + q * 16;
    const int wofs = r * LDW + q * 16;

    bf16x8_t sa0, sa1, sb0, sb1;
    auto load_regs = [&](int c) {
        const int k0 = c * BK;
        sa0 = *(const bf16x8_t*)(ga + k0);
        sa1 = *(const bf16x8_t*)(ga + k0 + 8);
        sb0 = *(const bf16x8_t*)(gb + k0);
        sb1 = *(const bf16x8_t*)(gb + k0 + 8);
    };
    auto write_lds = [&](int buf) {
        *(bf16x8_t*)(&ldsA[buf][wofs])     = sa0;
        *(bf16x8_t*)(&ldsA[buf][wofs + 8]) = sa1;
        *(bf16x8_t*)(&ldsB[buf][wofs])     = sb0;
        *(bf16x8_t*)(&ldsB[buf][wofs + 8]) = sb1;
    };

    f32x4_t acc[2][4];
    #pragma unroll
    for (int mi = 0; mi < 2; ++mi)
        #pragma unroll
        for (int nj = 0; nj < 4; ++nj)
            acc[mi][nj] = (f32x4_t){0.f, 0.f, 0.f, 0.f};

    auto compute = [&](int buf) {
        #pragma unroll
        for (int ks = 0; ks < 2; ++ks) {
            bf16x8_t af[2], bff[4];
            #pragma unroll
            for (int mi = 0; mi < 2; ++mi)
                af[mi] = *(const bf16x8_t*)(&ldsA[buf][(wr + mi * 16 + lane15) * LDW + ks * 32 + quad * 8]);
            #pragma unroll
            for (int nj = 0; nj < 4; ++nj)
                bff[nj] = *(const bf16x8_t*)(&ldsB[buf][(wc + nj * 16 + lane15) * LDW + ks * 32 + quad * 8]);
            #pragma unroll
            for (int mi = 0; mi < 2; ++mi)
                #pragma unroll
                for (int nj = 0; nj < 4; ++nj)
                    acc[mi][nj] = __builtin_amdgcn_mfma_f32_16x16x32_bf16(bff[nj], af[mi], acc[mi][nj], 0, 0, 0);
        }
    };

    load_regs(0);
    write_lds(0);
    __syncthreads();

    int cur = 0;
    #pragma unroll
    for (int c = 0; c < NCH; ++c) {
        if (c + 1 < NCH) load_regs(c + 1);
        compute(cur);
        if (c + 1 < NCH) {
            write_lds(cur ^ 1);
            __syncthreads();
            cur ^= 1;
        }
    }

    // epilogue: rows -> bi panel; cols (off-diag) -> bj panel; positives at bj==bi+32
    const bool posBlk = (bj == bi + 32);
    float rs[2] = {0.f, 0.f};
    float cp[4][4];
    #pragma unroll
    for (int nj = 0; nj < 4; ++nj)
        #pragma unroll
        for (int t = 0; t < 4; ++t) cp[nj][t] = 0.f;

    #pragma unroll
    for (int mi = 0; mi < 2; ++mi) {
        #pragma unroll
        for (int nj = 0; nj < 4; ++nj) {
            const bool fd = (wr + mi * 16 == wc + nj * 16);   // fragment on tile diag
            const bool dn = diag && fd;
            const bool dp = posBlk && fd;
            #pragma unroll
            for (int t = 0; t < 4; ++t) {
                float e = exp2f(acc[mi][nj][t] * 2.8853900817779268f);
                if (dn && (quad * 4 + t) == lane15) e = 0.0f;
                if (dp && (quad * 4 + t) == lane15)
                    __hip_atomic_store(&g_pos[bi * TILE + wr + mi * 16 + lane15],
                                       acc[mi][nj][t], __ATOMIC_RELAXED,
                                       __HIP_MEMORY_SCOPE_AGENT);
                rs[mi] += e;
                cp[nj][t] += e;
            }
        }
    }
    #pragma unroll
    for (int mi = 0; mi < 2; ++mi) {
        rs[mi] += __shfl_xor(rs[mi], 16, 64);
        rs[mi] += __shfl_xor(rs[mi], 32, 64);
    }
    if (l < 16) {
        #pragma unroll
        for (int mi = 0; mi < 2; ++mi)
            atomicAdd(&g_denom[bi * TILE + wr + mi * 16 + l], rs[mi]);
    }
    if (!diag) {   // recursive-halving col reduce (r16-verified), one 64-lane atomic
        float s8[8], s4[4], s2[2], s;
        #pragma unroll
        for (int i = 0; i < 8; ++i) {
            const float lo = cp[i >> 2][i & 3];
            const float hi = cp[(i + 8) >> 2][(i + 8) & 3];
            const float send = (lane15 & 8) ? lo : hi;
            const float recv = __shfl_xor(send, 8, 64);
            s8[i] = ((lane15 & 8) ? hi : lo) + recv;
        }
        #pragma unroll
        for (int i = 0; i < 4; ++i) {
            const float send = (lane15 & 4) ? s8[i] : s8[i + 4];
            const float recv = __shfl_xor(send, 4, 64);
            s4[i] = ((lane15 & 4) ? s8[i + 4] : s8[i]) + recv;
        }
        #pragma unroll
        for (int i = 0; i < 2; ++i) {
            const float send = (lane15 & 2) ? s4[i] : s4[i + 2];
            const float recv = __shfl_xor(send, 2, 64);
            s2[i] = ((lane15 & 2) ? s4[i + 2] : s4[i]) + recv;
        }
        {
            const float send = (lane15 & 1) ? s2[0] : s2[1];
            const float recv = __shfl_xor(send, 1, 64);
            s = ((lane15 & 1) ? s2[1] : s2[0]) + recv;
        }
        atomicAdd(&g_denom[bj * TILE + wc + (lane15 >> 2) * 16 + quad * 4 + (lane15 & 3)], s);
    }

    // ---------------- two-level fenceless ticket fin (r16-verified) ----------------
    __syncthreads();
    if (tid == 0) {
        asm volatile("s_waitcnt vmcnt(0)" ::: "memory");
        unsigned t1 = __hip_atomic_fetch_add(&g_t1[(bx >> 5) * 32], 1u,
                                             __ATOMIC_RELAXED, __HIP_MEMORY_SCOPE_AGENT);
        bool grpLast = (t1 == 31);
        unsigned t2 = 0;
        if (grpLast)
            t2 = __hip_atomic_fetch_add(&g_t1[65 * 32], 1u, __ATOMIC_RELAXED,
                                        __HIP_MEMORY_SCOPE_AGENT);
        amLast = grpLast && (t2 == 64);
    }
    __syncthreads();
    if (!amLast) return;

    float local = 0.0f;
    for (int kk = tid; kk < N2; kk += TPB) {
        float dn = __hip_atomic_load(&g_denom[kk], __ATOMIC_RELAXED,
                                     __HIP_MEMORY_SCOPE_AGENT);
        local += logf(dn);
        if (kk < NHALF) {
            float p = __hip_atomic_load(&g_pos[kk], __ATOMIC_RELAXED,
                                        __HIP_MEMORY_SCOPE_AGENT);
            local -= 4.0f * p;
        }
    }
    #pragma unroll
    for (int off = 32; off; off >>= 1) local += __shfl_xor(local, off, 64);
    if (l == 0) sw[w] = local;
    __syncthreads();
    if (tid == 0) {
        float s = 0.f;
        #pragma unroll
        for (int i = 0; i < 8; ++i) s += sw[i];
        out[0] = s / (float)N2;
    }
}

extern "C" void kernel_launch(void* const* d_in, const int* in_sizes, int n_in,
                              void* d_out, int out_size, void* d_ws, size_t ws_size,
                              hipStream_t stream) {
    const float* emb_i = (const float*)d_in[0];
    const float* emb_j = (const float*)d_in[1];

    // layout: [g_denom 8192 f32][g_t1 2088 u32][g_flag 64 u32] (memset-zeroed)
    //         | zb 4MB (claim-written) | g_pos 4096 f32 (written before read)
    float*    g_denom = (float*)d_ws;
    unsigned* g_t1    = (unsigned*)(g_denom + N2);          // 65*32+1 -> pad 2088
    unsigned* g_flag  = g_t1 + 2088;                        // 64 panel flags
    __bf16*   zb      = (__bf16*)((char*)d_ws + 41472);     // 128B-aligned
    float*    g_pos   = (float*)(zb + (size_t)N2 * D);
    float*    out     = (float*)d_out;

    hipMemsetAsync(d_ws, 0, (size_t)(N2 * 4 + 2088 * 4 + 64 * 4), stream);
    sim_kernel<<<NTRI, TPB, 0, stream>>>(emb_i, emb_j, zb, g_denom, g_pos,
                                         g_t1, g_flag, out);
}